// Round 5
// baseline (55.650 us; speedup 1.0000x reference)
//
#include <hip/hip_runtime.h>

// Problem constants (match reference)
#define VOCAB 32000
#define EXTRA 256
#define D     2048
#define R     16
#define L     8
#define T     16384
#define BS    16
#define SEG   (T / BS)   // 1024

#define TB   16          // tokens per block (best measured; small blocks load-balance)
#define DC   1024        // d-columns per block (256 thr * 4 floats)
#define RING 8           // rotating prefetch depth (tokens in flight)

typedef float f32x4 __attribute__((ext_vector_type(4)));

__global__ __launch_bounds__(256, 4) void emb_lora_kernel(
    const int*   __restrict__ input_ids,
    const int*   __restrict__ weight_indices,
    const float* __restrict__ W,
    const float* __restrict__ new_emb,   // (L, EXTRA, D)
    const float* __restrict__ A,         // (L, R, VOCAB+EXTRA)
    const float* __restrict__ B,         // (L, D, R)
    float*       __restrict__ out)       // (T, D)
{
    const int dchunk = blockIdx.x;              // 0..D/DC-1 (fastest: row-sharing blocks adjacent)
    const int tg     = blockIdx.y;              // token group within segment
    const int b      = blockIdx.z;              // segment index 0..BS-1
    const int tid    = threadIdx.x;

    const int l  = weight_indices[b];           // block-uniform -> scalar
    const int d0 = dchunk * DC + tid * 4;       // this thread's 4 output columns
    const int t0 = b * SEG + tg * TB;           // first token of this group

    // Block-uniform row pointer for token tt. input_ids[t0+tt] has a uniform
    // address -> scalar-cache load; pointer math stays on the scalar pipe.
    auto rowptr = [&](int tt) -> const float* {
        const int id = __builtin_amdgcn_readfirstlane(input_ids[t0 + tt]);
        return (id >= VOCAB)
            ? (new_emb + ((size_t)l * EXTRA + (id - VOCAB)) * D)
            : (W + (size_t)id * D);
    };

    // ---- issue the first RING base-row gathers IMMEDIATELY (no barrier dep) ----
    f32x4 bv[RING];
    #pragma unroll
    for (int k = 0; k < RING; ++k)
        bv[k] = *reinterpret_cast<const f32x4*>(rowptr(k) + d0);

    // ---- stage lora_a gather into LDS (overlaps with bv loads in flight) ----
    __shared__ f32x4 s_a4[TB][4];     // s_a[tt][r] as 4x float4 per token
    {
        const int tt = tid >> 4;       // token within group
        const int r  = tid & 15;       // rank index
        const int id = input_ids[t0 + tt];   // 16 lanes share one line
        reinterpret_cast<float*>(&s_a4[tt][0])[r] =
            A[((size_t)l * R + r) * (VOCAB + EXTRA) + id];
    }

    // ---- B rows for my 4 columns -> registers (fixed across tokens) ----
    float breg[4][R];
    {
        const float* Bl = B + ((size_t)l * D + d0) * R;
        #pragma unroll
        for (int j = 0; j < 4; ++j) {
            #pragma unroll
            for (int q = 0; q < 4; ++q) {
                f32x4 v = *reinterpret_cast<const f32x4*>(Bl + (size_t)j * R + q * 4);
                breg[j][q * 4 + 0] = v.x;
                breg[j][q * 4 + 1] = v.y;
                breg[j][q * 4 + 2] = v.z;
                breg[j][q * 4 + 3] = v.w;
            }
        }
    }
    __syncthreads();

    // ---- rotating 8-deep prefetch: loads stay in flight during compute ----
    #pragma unroll
    for (int tt = 0; tt < TB; ++tt) {
        f32x4 cur = bv[tt & (RING - 1)];            // waits on this slot only
        if (tt + RING < TB)                          // refill slot immediately
            bv[tt & (RING - 1)] =
                *reinterpret_cast<const f32x4*>(rowptr(tt + RING) + d0);

        float rx = cur.x, ry = cur.y, rz = cur.z, rw = cur.w;
        #pragma unroll
        for (int q = 0; q < 4; ++q) {
            f32x4 a4 = s_a4[tt][q];                  // ds_read_b128 broadcast
            rx = fmaf(a4.x, breg[0][q*4+0], rx);
            ry = fmaf(a4.x, breg[1][q*4+0], ry);
            rz = fmaf(a4.x, breg[2][q*4+0], rz);
            rw = fmaf(a4.x, breg[3][q*4+0], rw);
            rx = fmaf(a4.y, breg[0][q*4+1], rx);
            ry = fmaf(a4.y, breg[1][q*4+1], ry);
            rz = fmaf(a4.y, breg[2][q*4+1], rz);
            rw = fmaf(a4.y, breg[3][q*4+1], rw);
            rx = fmaf(a4.z, breg[0][q*4+2], rx);
            ry = fmaf(a4.z, breg[1][q*4+2], ry);
            rz = fmaf(a4.z, breg[2][q*4+2], rz);
            rw = fmaf(a4.z, breg[3][q*4+2], rw);
            rx = fmaf(a4.w, breg[0][q*4+3], rx);
            ry = fmaf(a4.w, breg[1][q*4+3], ry);
            rz = fmaf(a4.w, breg[2][q*4+3], rz);
            rw = fmaf(a4.w, breg[3][q*4+3], rw);
        }

        f32x4 res = {rx, ry, rz, rw};
        // write-once stream: nontemporal, don't evict W from L2/L3
        __builtin_nontemporal_store(
            res, reinterpret_cast<f32x4*>(out + (size_t)(t0 + tt) * D + d0));
    }
}

extern "C" void kernel_launch(void* const* d_in, const int* in_sizes, int n_in,
                              void* d_out, int out_size, void* d_ws, size_t ws_size,
                              hipStream_t stream) {
    const int*   input_ids      = (const int*)  d_in[0];  // (T,)
    const int*   weight_indices = (const int*)  d_in[1];  // (BS,)
    const float* W              = (const float*)d_in[2];  // (VOCAB, D)
    const float* new_emb        = (const float*)d_in[3];  // (L, EXTRA, D)
    const float* A              = (const float*)d_in[4];  // (L, R, VOCAB+EXTRA)
    const float* B              = (const float*)d_in[5];  // (L, D, R)
    float*       out            = (float*)      d_out;    // (T, D)

    dim3 grid(D / DC, SEG / TB, BS);   // (2, 64, 16) = 2048 blocks, dchunk fastest
    dim3 block(256);
    emb_lora_kernel<<<grid, block, 0, stream>>>(
        input_ids, weight_indices, W, new_emb, A, B, out);
}

// Round 6
// 52.557 us; speedup vs baseline: 1.0589x; 1.0589x over previous
//
#include <hip/hip_runtime.h>

// Problem constants (match reference)
#define VOCAB 32000
#define EXTRA 256
#define D     2048
#define R     16
#define L     8
#define T     16384
#define BS    16
#define SEG   (T / BS)   // 1024

#define TB   16          // tokens per block
#define DC   1024        // d-columns per block (256 thr * 4 floats)
#define RING 8           // rotating prefetch depth (tokens in flight)

typedef float f32x4 __attribute__((ext_vector_type(4)));

__global__ __launch_bounds__(256, 4) void emb_lora_kernel(
    const int*   __restrict__ input_ids,
    const int*   __restrict__ weight_indices,
    const float* __restrict__ W,
    const float* __restrict__ new_emb,   // (L, EXTRA, D)
    const float* __restrict__ A,         // (L, R, VOCAB+EXTRA)
    const float* __restrict__ B,         // (L, D, R)
    float*       __restrict__ out)       // (T, D)
{
    const int b      = blockIdx.z;              // segment index 0..BS-1
    const int dchunk = blockIdx.y;              // 0..D/DC-1
    const int tg     = blockIdx.x;              // token group within segment (fastest)
    const int tid    = threadIdx.x;

    const int l  = weight_indices[b];
    const int d0 = dchunk * DC + tid * 4;       // this thread's 4 output columns
    const int t0 = b * SEG + tg * TB;           // first token of this group

    // ---- B rows for my 4 columns -> registers (fixed across tokens) ----
    float breg[4][R];
    {
        const float* Bl = B + ((size_t)l * D + d0) * R;
        #pragma unroll
        for (int j = 0; j < 4; ++j) {
            #pragma unroll
            for (int q = 0; q < 4; ++q) {
                f32x4 v = *reinterpret_cast<const f32x4*>(Bl + (size_t)j * R + q * 4);
                breg[j][q * 4 + 0] = v.x;
                breg[j][q * 4 + 1] = v.y;
                breg[j][q * 4 + 2] = v.z;
                breg[j][q * 4 + 3] = v.w;
            }
        }
    }

    // ---- stage token ids + lora_a gather into LDS (single barrier) ----
    __shared__ int   s_id[TB];
    __shared__ f32x4 s_a4[TB][4];     // s_a[tt][r] as 4x float4 per token

    {
        const int tt = tid >> 4;       // token within group
        const int r  = tid & 15;       // rank index
        const int id = input_ids[t0 + tt];   // 16 lanes share one line (L1 hit)
        reinterpret_cast<float*>(&s_a4[tt][0])[r] =
            A[((size_t)l * R + r) * (VOCAB + EXTRA) + id];
        if (r == 0) s_id[tt] = id;     // reuse in-register id, no extra load
    }
    __syncthreads();

    // wave-uniform row pointer for token tt (scalar-pipe address math)
    auto rowptr = [&](int tt) -> const float* {
        const int id = __builtin_amdgcn_readfirstlane(s_id[tt]);
        return (id >= VOCAB)
            ? (new_emb + ((size_t)l * EXTRA + (id - VOCAB)) * D)
            : (W + (size_t)id * D);
    };

    // ---- rotating 8-deep prefetch: loads stay in flight during compute ----
    f32x4 bv[RING];
    #pragma unroll
    for (int k = 0; k < RING; ++k)
        bv[k] = *reinterpret_cast<const f32x4*>(rowptr(k) + d0);

    #pragma unroll
    for (int tt = 0; tt < TB; ++tt) {
        f32x4 cur = bv[tt & (RING - 1)];            // waits on this slot only
        if (tt + RING < TB)                          // refill slot immediately
            bv[tt & (RING - 1)] =
                *reinterpret_cast<const f32x4*>(rowptr(tt + RING) + d0);

        float rx = cur.x, ry = cur.y, rz = cur.z, rw = cur.w;
        #pragma unroll
        for (int q = 0; q < 4; ++q) {
            f32x4 a4 = s_a4[tt][q];                  // ds_read_b128 broadcast
            rx = fmaf(a4.x, breg[0][q*4+0], rx);
            ry = fmaf(a4.x, breg[1][q*4+0], ry);
            rz = fmaf(a4.x, breg[2][q*4+0], rz);
            rw = fmaf(a4.x, breg[3][q*4+0], rw);
            rx = fmaf(a4.y, breg[0][q*4+1], rx);
            ry = fmaf(a4.y, breg[1][q*4+1], ry);
            rz = fmaf(a4.y, breg[2][q*4+1], rz);
            rw = fmaf(a4.y, breg[3][q*4+1], rw);
            rx = fmaf(a4.z, breg[0][q*4+2], rx);
            ry = fmaf(a4.z, breg[1][q*4+2], ry);
            rz = fmaf(a4.z, breg[2][q*4+2], rz);
            rw = fmaf(a4.z, breg[3][q*4+2], rw);
            rx = fmaf(a4.w, breg[0][q*4+3], rx);
            ry = fmaf(a4.w, breg[1][q*4+3], ry);
            rz = fmaf(a4.w, breg[2][q*4+3], rz);
            rw = fmaf(a4.w, breg[3][q*4+3], rw);
        }

        f32x4 res = {rx, ry, rz, rw};
        // write-once stream: nontemporal, don't evict W from L2/L3
        __builtin_nontemporal_store(
            res, reinterpret_cast<f32x4*>(out + (size_t)(t0 + tt) * D + d0));
    }
}

extern "C" void kernel_launch(void* const* d_in, const int* in_sizes, int n_in,
                              void* d_out, int out_size, void* d_ws, size_t ws_size,
                              hipStream_t stream) {
    const int*   input_ids      = (const int*)  d_in[0];  // (T,)
    const int*   weight_indices = (const int*)  d_in[1];  // (BS,)
    const float* W              = (const float*)d_in[2];  // (VOCAB, D)
    const float* new_emb        = (const float*)d_in[3];  // (L, EXTRA, D)
    const float* A              = (const float*)d_in[4];  // (L, R, VOCAB+EXTRA)
    const float* B              = (const float*)d_in[5];  // (L, D, R)
    float*       out            = (float*)      d_out;    // (T, D)

    dim3 grid(SEG / TB, D / DC, BS);   // (64, 2, 16) = 2048 blocks, tg fastest
    dim3 block(256);
    emb_lora_kernel<<<grid, block, 0, stream>>>(
        input_ids, weight_indices, W, new_emb, A, B, out);
}